// Round 10
// baseline (8877.187 us; speedup 1.0000x reference)
//
#include <hip/hip_runtime.h>
#include <math.h>

#define LNUM 16
#define D 256
#define FF 512
#define NH 8
#define NE 12
#define HD 32
#define BB 4
#define SS 512
#define NT 2048      // B*S
#define EPS 1e-5f
#define MAXT 48
#define PADROWS 5632
#define GRIDN 256

typedef _Float16 f16;
typedef __attribute__((ext_vector_type(8))) _Float16 f16x8;
typedef __attribute__((ext_vector_type(4))) _Float16 f16x4;
typedef __attribute__((ext_vector_type(4))) float f32x4;
#define MFMA(A, B, C) __builtin_amdgcn_mfma_f32_16x16x32_f16((A), (B), (C), 0, 0, 0)

__device__ inline void splitf(float x, f16& h, f16& l) {
  f16 hh = (f16)x;
  h = hh;
  l = (f16)(x - (float)hh);
}

// ---------------- software grid barrier (graph-capturable; device-scope) ----------------
// All 256 blocks co-resident (grid == #CUs, 1 block/CU). gen monotonic across replays;
// cnt==0 invariant at kernel entry/exit (k_bzero re-establishes after ws poison).
__device__ inline void gridbar(int* cnt, int* gen) {
  __syncthreads();
  if (threadIdx.x == 0) {
    __threadfence();  // release this block's writes (device scope)
    int g = __hip_atomic_load(gen, __ATOMIC_RELAXED, __HIP_MEMORY_SCOPE_AGENT);
    int a = __hip_atomic_fetch_add(cnt, 1, __ATOMIC_ACQ_REL, __HIP_MEMORY_SCOPE_AGENT);
    if (a == GRIDN - 1) {
      __hip_atomic_store(cnt, 0, __ATOMIC_RELAXED, __HIP_MEMORY_SCOPE_AGENT);
      __hip_atomic_fetch_add(gen, 1, __ATOMIC_ACQ_REL, __HIP_MEMORY_SCOPE_AGENT);
    } else {
      int spins = 0;
      while (__hip_atomic_load(gen, __ATOMIC_ACQUIRE, __HIP_MEMORY_SCOPE_AGENT) == g) {
        __builtin_amdgcn_s_sleep(2);
        if (++spins > (1 << 17)) break;  // bailout: wrong-answer signal, never a hang
      }
    }
    __threadfence();  // acquire other blocks' writes
  }
  __syncthreads();
}

__global__ void k_bzero(int* bcnt) { *bcnt = 0; }

// ---------------- weight prep: [K][N] fp32 -> hi/lo [N][K] f16 (per-mat z) ----------------
__global__ __launch_bounds__(256) void k_wprep(const float* __restrict__ src,
                                               f16* __restrict__ dh, f16* __restrict__ dl,
                                               int K, int N) {
  const size_t msz = (size_t)K * N * blockIdx.z;
  src += msz; dh += msz; dl += msz;
  const int n0 = blockIdx.x * 32, k0 = blockIdx.y * 32;
  __shared__ f16 th[32][33], tl[32][33];
  const int t = threadIdx.x;
  {
    const int r = t >> 3, c4 = (t & 7) * 4;
    float4 v = *(const float4*)(src + (size_t)(k0 + r) * N + n0 + c4);
    f16 h0, l0, h1, l1, h2, l2, h3, l3;
    splitf(v.x, h0, l0); splitf(v.y, h1, l1);
    splitf(v.z, h2, l2); splitf(v.w, h3, l3);
    th[c4 + 0][r] = h0; tl[c4 + 0][r] = l0;
    th[c4 + 1][r] = h1; tl[c4 + 1][r] = l1;
    th[c4 + 2][r] = h2; tl[c4 + 2][r] = l2;
    th[c4 + 3][r] = h3; tl[c4 + 3][r] = l3;
  }
  __syncthreads();
  const int rn = t >> 3, ck = (t & 7) * 4;
  f16x4 hv, lv;
#pragma unroll
  for (int j = 0; j < 4; j++) { hv[j] = th[rn][ck + j]; lv[j] = tl[rn][ck + j]; }
  *(f16x4*)(dh + (size_t)(n0 + rn) * K + k0 + ck) = hv;
  *(f16x4*)(dl + (size_t)(n0 + rn) * K + k0 + ck) = lv;
}

// ---------------- megakernel shared-memory union ----------------
struct QkvS { f16 Ah[128][44]; f16 Al[128][44]; f16 Bh[64][44]; f16 Bl[64][44]; };
struct AttnS {
  f16 Qh[64][40]; f16 Ql[64][40]; f16 Kh[64][40]; f16 Kl[64][40];
  f16 Vth[32][72]; f16 Vtl[32][72];
  f16 Ph[4][16][72]; f16 Pl[4][16][72];
};
struct Ff1S {
  f16 Ah[128][44]; f16 Al[128][44];
  f16 B1h[64][44]; f16 B1l[64][44]; f16 B2h[64][44]; f16 B2l[64][44];
  int rows[128];
};
struct Ff2S { f16 Ah[128][44]; f16 Al[128][44]; f16 Bh[64][44]; f16 Bl[64][44]; };
struct RouteS { int cnt[NE]; int cur[NE]; int poff[NE]; };
union SmemU { QkvS q; AttnS a; Ff1S f1; Ff2S f2; RouteS r; };

struct MP {
  const int* tok; const float* emb;
  const float *bq, *bk, *bv;
  const float *l1s, *l1b, *l2s, *l2b, *gW, *gb;
  const float *f1b, *fgb, *f2b;
  const f16 *wqh, *wql, *wkh, *wkl, *wvh, *wvl;
  const f16 *w1th, *w1tl, *wgth, *wgtl, *w2th, *w2tl;
  float *xb, *ob, *nb, *yb, *out;
  f16 *xh, *xl, *qhb, *qlb, *khb, *klb, *vhb, *vlb, *nhb, *nlb, *hhb, *hlb;
  int *eidx, *rlist, *tokpos, *te, *tbase, *tnv;
  int *bcnt, *bgen;
};

__global__ __launch_bounds__(256, 1) void k_mega(MP P) {
  __shared__ SmemU sm;
  const int bid = blockIdx.x;       // 0..255
  const int tid = threadIdx.x;
  const int lane = tid & 63, w = tid >> 6;
  const int lm = lane & 15, lg = lane >> 4, lk = lg * 8;

  // ======== phase: embed + split ========
  for (int n = bid; n < NT; n += GRIDN) {
    float val = P.emb[(size_t)P.tok[n] * D + tid];
    P.xb[(size_t)n * D + tid] = val;
    f16 h, l; splitf(val, h, l);
    P.xh[(size_t)n * D + tid] = h;
    P.xl[(size_t)n * D + tid] = l;
  }
  gridbar(P.bcnt, P.bgen);

  for (int l = 0; l < LNUM; l++) {
    const f16* wqh = P.wqh + (size_t)l * D * D;
    const f16* wql = P.wql + (size_t)l * D * D;
    const f16* wkh = P.wkh + (size_t)l * D * D;
    const f16* wkl = P.wkl + (size_t)l * D * D;
    const f16* wvh = P.wvh + (size_t)l * D * D;
    const f16* wvl = P.wvl + (size_t)l * D * D;
    const float* bq = P.bq + (size_t)l * D;
    const float* bk = P.bk + (size_t)l * D;
    const float* bv = P.bv + (size_t)l * D;
    const float* l1s = P.l1s + (size_t)l * D;
    const float* l1b = P.l1b + (size_t)l * D;
    const float* l2s = P.l2s + (size_t)l * D;
    const float* l2b = P.l2b + (size_t)l * D;
    const float* gW = P.gW + (size_t)l * D * NE;
    const float* gb = P.gb + (size_t)l * NE;
    const f16* w1th = P.w1th + (size_t)l * NE * D * FF;
    const f16* w1tl = P.w1tl + (size_t)l * NE * D * FF;
    const f16* wgth = P.wgth + (size_t)l * NE * D * FF;
    const f16* wgtl = P.wgtl + (size_t)l * NE * D * FF;
    const f16* w2th = P.w2th + (size_t)l * NE * FF * D;
    const f16* w2tl = P.w2tl + (size_t)l * NE * FF * D;
    const float* b1f = P.f1b + (size_t)l * NE * FF;
    const float* bgf = P.fgb + (size_t)l * NE * FF;
    const float* b2f = P.f2b + (size_t)l * NE * D;

    // ======== phase: QKV (192 tiles) ========
    if (bid < 192) {
      const int bx = bid & 15, by = (bid >> 4) & 3, mat = bid >> 6;
      const f16* Wh; const f16* Wl; const float* bias; f16* outh; f16* outl;
      if (mat == 0)      { Wh = wqh; Wl = wql; bias = bq; outh = P.qhb; outl = P.qlb; }
      else if (mat == 1) { Wh = wkh; Wl = wkl; bias = bk; outh = P.khb; outl = P.klb; }
      else               { Wh = wvh; Wl = wvl; bias = bv; outh = P.vhb; outl = P.vlb; }
      const int row0 = bx * 128, col0 = by * 64;
      const int asr = tid >> 1, asc = (tid & 1) * 16;
      const int bn2 = tid >> 2, bkc = (tid & 3) * 8;
      f32x4 acc[2][4] = {};
      for (int k0 = 0; k0 < D; k0 += 32) {
        {
          size_t ga = (size_t)(row0 + asr) * D + k0 + asc;
          *(f16x8*)&sm.q.Ah[asr][asc]     = *(const f16x8*)(P.xh + ga);
          *(f16x8*)&sm.q.Ah[asr][asc + 8] = *(const f16x8*)(P.xh + ga + 8);
          *(f16x8*)&sm.q.Al[asr][asc]     = *(const f16x8*)(P.xl + ga);
          *(f16x8*)&sm.q.Al[asr][asc + 8] = *(const f16x8*)(P.xl + ga + 8);
          size_t gb2 = (size_t)(col0 + bn2) * D + k0 + bkc;
          *(f16x8*)&sm.q.Bh[bn2][bkc] = *(const f16x8*)(Wh + gb2);
          *(f16x8*)&sm.q.Bl[bn2][bkc] = *(const f16x8*)(Wl + gb2);
        }
        __syncthreads();
        f16x8 a_h[2], a_l[2];
#pragma unroll
        for (int mt = 0; mt < 2; mt++) {
          a_h[mt] = *(const f16x8*)&sm.q.Ah[w * 32 + mt * 16 + lm][lk];
          a_l[mt] = *(const f16x8*)&sm.q.Al[w * 32 + mt * 16 + lm][lk];
        }
#pragma unroll
        for (int nt = 0; nt < 4; nt++) {
          f16x8 b_h = *(const f16x8*)&sm.q.Bh[nt * 16 + lm][lk];
          f16x8 b_l = *(const f16x8*)&sm.q.Bl[nt * 16 + lm][lk];
#pragma unroll
          for (int mt = 0; mt < 2; mt++) {
            f32x4 c = acc[mt][nt];
            c = MFMA(a_h[mt], b_h, c);
            c = MFMA(a_h[mt], b_l, c);
            c = MFMA(a_l[mt], b_h, c);
            acc[mt][nt] = c;
          }
        }
        __syncthreads();
      }
#pragma unroll
      for (int mt = 0; mt < 2; mt++)
#pragma unroll
        for (int nt = 0; nt < 4; nt++) {
          int col = col0 + nt * 16 + lm;
          float bv_ = bias[col];
#pragma unroll
          for (int r = 0; r < 4; r++) {
            int row = row0 + w * 32 + mt * 16 + lg * 4 + r;
            float val = acc[mt][nt][r] + bv_;
            f16 h16, l16; splitf(val, h16, l16);
            outh[(size_t)row * D + col] = h16;
            outl[(size_t)row * D + col] = l16;
          }
        }
    }
    gridbar(P.bcnt, P.bgen);

    // ======== phase: attention (256 tiles) ========
    {
      const int rt = bid >> 5, bh = bid & 31;
      const int b = bh >> 3, h = bh & 7;
      const int row0 = rt * 64;
      const int sr = tid >> 2, sc = (tid & 3) * 8;
      {
        size_t gq = (size_t)(b * SS + row0 + sr) * D + h * HD + sc;
        *(f16x8*)&sm.a.Qh[sr][sc] = *(const f16x8*)(P.qhb + gq);
        *(f16x8*)&sm.a.Ql[sr][sc] = *(const f16x8*)(P.qlb + gq);
      }
      f32x4 accO[2] = {};
      float mrow[4], lsum[4];
#pragma unroll
      for (int r = 0; r < 4; r++) { mrow[r] = -1e30f; lsum[r] = 0.f; }
      for (int ct = 0; ct <= rt; ct++) {
        __syncthreads();
        {
          size_t gk = (size_t)(b * SS + ct * 64 + sr) * D + h * HD + sc;
          *(f16x8*)&sm.a.Kh[sr][sc] = *(const f16x8*)(P.khb + gk);
          *(f16x8*)&sm.a.Kl[sr][sc] = *(const f16x8*)(P.klb + gk);
          f16x8 hv = *(const f16x8*)(P.vhb + gk);
          f16x8 lv = *(const f16x8*)(P.vlb + gk);
#pragma unroll
          for (int j = 0; j < 8; j++) { sm.a.Vth[sc + j][sr] = hv[j]; sm.a.Vtl[sc + j][sr] = lv[j]; }
        }
        __syncthreads();
        f16x8 qfh = *(const f16x8*)&sm.a.Qh[w * 16 + lm][lk];
        f16x8 qfl = *(const f16x8*)&sm.a.Ql[w * 16 + lm][lk];
        f32x4 s[4];
#pragma unroll
        for (int nt = 0; nt < 4; nt++) {
          f16x8 kfh = *(const f16x8*)&sm.a.Kh[nt * 16 + lm][lk];
          f16x8 kfl = *(const f16x8*)&sm.a.Kl[nt * 16 + lm][lk];
          f32x4 c = {};
          c = MFMA(qfh, kfh, c);
          c = MFMA(qfh, kfl, c);
          c = MFMA(qfl, kfh, c);
          s[nt] = c;
        }
        if (ct == rt) {
#pragma unroll
          for (int nt = 0; nt < 4; nt++)
#pragma unroll
            for (int r = 0; r < 4; r++)
              if (nt * 16 + lm > w * 16 + lg * 4 + r) s[nt][r] = -1e30f;
        }
        float scal[4];
#pragma unroll
        for (int r = 0; r < 4; r++) {
          float mt2 = fmaxf(fmaxf(s[0][r], s[1][r]), fmaxf(s[2][r], s[3][r]));
          mt2 = fmaxf(mt2, __shfl_xor(mt2, 1));
          mt2 = fmaxf(mt2, __shfl_xor(mt2, 2));
          mt2 = fmaxf(mt2, __shfl_xor(mt2, 4));
          mt2 = fmaxf(mt2, __shfl_xor(mt2, 8));
          float mn = fmaxf(mrow[r], mt2);
          scal[r] = expf(mrow[r] - mn);
          mrow[r] = mn;
        }
        float rs[4] = {0.f, 0.f, 0.f, 0.f};
#pragma unroll
        for (int nt = 0; nt < 4; nt++)
#pragma unroll
          for (int r = 0; r < 4; r++) {
            float pv = expf(s[nt][r] - mrow[r]);
            rs[r] += pv;
            f16 ph16, pl16; splitf(pv, ph16, pl16);
            sm.a.Ph[w][lg * 4 + r][nt * 16 + lm] = ph16;
            sm.a.Pl[w][lg * 4 + r][nt * 16 + lm] = pl16;
          }
#pragma unroll
        for (int r = 0; r < 4; r++) {
          rs[r] += __shfl_xor(rs[r], 1);
          rs[r] += __shfl_xor(rs[r], 2);
          rs[r] += __shfl_xor(rs[r], 4);
          rs[r] += __shfl_xor(rs[r], 8);
          lsum[r] = lsum[r] * scal[r] + rs[r];
          accO[0][r] *= scal[r];
          accO[1][r] *= scal[r];
        }
#pragma unroll
        for (int ct2 = 0; ct2 < 2; ct2++)
#pragma unroll
          for (int ks = 0; ks < 2; ks++) {
            f16x8 pa_h = *(const f16x8*)&sm.a.Ph[w][lm][ks * 32 + lk];
            f16x8 pa_l = *(const f16x8*)&sm.a.Pl[w][lm][ks * 32 + lk];
            f16x8 vb_h = *(const f16x8*)&sm.a.Vth[ct2 * 16 + lm][ks * 32 + lk];
            f16x8 vb_l = *(const f16x8*)&sm.a.Vtl[ct2 * 16 + lm][ks * 32 + lk];
            accO[ct2] = MFMA(pa_h, vb_h, accO[ct2]);
            accO[ct2] = MFMA(pa_h, vb_l, accO[ct2]);
            accO[ct2] = MFMA(pa_l, vb_h, accO[ct2]);
          }
      }
#pragma unroll
      for (int ct2 = 0; ct2 < 2; ct2++)
#pragma unroll
        for (int r = 0; r < 4; r++) {
          int grow = row0 + w * 16 + lg * 4 + r;
          P.ob[(size_t)(b * SS + grow) * D + h * HD + ct2 * 16 + lm] = accO[ct2][r] / lsum[r];
        }
    }
    gridbar(P.bcnt, P.bgen);

    // ======== phase: LN1 + gate + top-2 (512 groups, 2 per block) ========
    for (int g2 = 0; g2 < 2; g2++) {
      const int n = (bid + g2 * GRIDN) * 4 + w;
      float val[4], s1v = 0.f, s2v = 0.f;
#pragma unroll
      for (int j = 0; j < 4; j++) {
        int d = lane + 64 * j;
        float v = P.ob[(size_t)n * D + d] + P.xb[(size_t)n * D + d];
        val[j] = v; s1v += v; s2v += v * v;
      }
#pragma unroll
      for (int m = 1; m < 64; m <<= 1) {
        s1v += __shfl_xor(s1v, m);
        s2v += __shfl_xor(s2v, m);
      }
      float mean = s1v * (1.f / D);
      float var = s2v * (1.f / D) - mean * mean;
      float rstd = rsqrtf(var + EPS);
      float ge[NE];
#pragma unroll
      for (int e = 0; e < NE; e++) ge[e] = 0.f;
#pragma unroll
      for (int j = 0; j < 4; j++) {
        int d = lane + 64 * j;
        float nv = (val[j] - mean) * rstd * l1s[d] + l1b[d];
        P.nb[(size_t)n * D + d] = nv;
        f16 h16, l16; splitf(nv, h16, l16);
        P.nhb[(size_t)n * D + d] = h16;
        P.nlb[(size_t)n * D + d] = l16;
        const float* gr = gW + (size_t)d * NE;
#pragma unroll
        for (int e = 0; e < NE; e++) ge[e] += nv * gr[e];
      }
#pragma unroll
      for (int m = 1; m < 64; m <<= 1)
#pragma unroll
        for (int e = 0; e < NE; e++) ge[e] += __shfl_xor(ge[e], m);
      if (lane == 0) {
#pragma unroll
        for (int e = 0; e < NE; e++) ge[e] += gb[e];
        int i1 = 0; float v1 = ge[0];
#pragma unroll
        for (int e = 1; e < NE; e++) if (ge[e] > v1) { v1 = ge[e]; i1 = e; }
        int i2 = -1; float v2 = -3.4e38f;
#pragma unroll
        for (int e = 0; e < NE; e++) if (e != i1 && ge[e] > v2) { v2 = ge[e]; i2 = e; }
        P.eidx[n * 2 + 0] = i1;
        P.eidx[n * 2 + 1] = i2;
      }
    }
    gridbar(P.bcnt, P.bgen);

    // ======== phase: route (block 0 only) ========
    if (bid == 0) {
      if (tid < NE) { sm.r.cnt[tid] = 0; sm.r.cur[tid] = 0; }
      __syncthreads();
      for (int n = tid; n < NT; n += 256) {
        atomicAdd(&sm.r.cnt[P.eidx[n * 2 + 0]], 1);
        atomicAdd(&sm.r.cnt[P.eidx[n * 2 + 1]], 1);
      }
      __syncthreads();
      if (tid == 0) {
        int off = 0, ti = 0;
        for (int e = 0; e < NE; e++) {
          sm.r.poff[e] = off;
          int ntl = (sm.r.cnt[e] + 127) >> 7;
          for (int tt = 0; tt < ntl; tt++) {
            P.te[ti] = e; P.tbase[ti] = off + tt * 128;
            int rem = sm.r.cnt[e] - tt * 128; P.tnv[ti] = rem < 128 ? rem : 128;
            ti++;
          }
          off += ntl * 128;
        }
        for (; ti < MAXT; ti++) P.te[ti] = -1;
      }
      __syncthreads();
      for (int n = tid; n < NT; n += 256) {
#pragma unroll
        for (int s2 = 0; s2 < 2; s2++) {
          int e = P.eidx[n * 2 + s2];
          int pos = atomicAdd(&sm.r.cur[e], 1);
          int row = sm.r.poff[e] + pos;
          P.rlist[row] = n;
          P.tokpos[n * 2 + s2] = row;
        }
      }
    }
    gridbar(P.bcnt, P.bgen);

    // ======== phase: FF1 (384 tiles, 2 passes) ========
    for (int pass = 0; pass < 2; pass++) {
      const int t = bid + pass * GRIDN;
      bool active = (t < 384);
      int mt0 = 0, cc = 0, e = -1;
      if (active) { mt0 = t % 48; cc = t / 48; e = P.te[mt0]; active = (e >= 0); }
      if (active) {
        const int base = P.tbase[mt0], nv = P.tnv[mt0];
        const int col0 = cc * 64;
        const f16* W1h = w1th + (size_t)e * D * FF + (size_t)col0 * D;
        const f16* W1l = w1tl + (size_t)e * D * FF + (size_t)col0 * D;
        const f16* Wgh = wgth + (size_t)e * D * FF + (size_t)col0 * D;
        const f16* Wgl = wgtl + (size_t)e * D * FF + (size_t)col0 * D;
        if (tid < 128) sm.f1.rows[tid] = (tid < nv) ? P.rlist[base + tid] : 0;
        __syncthreads();
        const int asr = tid >> 1, asc = (tid & 1) * 16;
        const int bn2 = tid >> 2, bkc = (tid & 3) * 8;
        f32x4 acc1[2][4] = {}, acc2[2][4] = {};
        const int arow = sm.f1.rows[asr];
        for (int k0 = 0; k0 < D; k0 += 32) {
          {
            size_t ga = (size_t)arow * D + k0 + asc;
            *(f16x8*)&sm.f1.Ah[asr][asc]     = *(const f16x8*)(P.nhb + ga);
            *(f16x8*)&sm.f1.Ah[asr][asc + 8] = *(const f16x8*)(P.nhb + ga + 8);
            *(f16x8*)&sm.f1.Al[asr][asc]     = *(const f16x8*)(P.nlb + ga);
            *(f16x8*)&sm.f1.Al[asr][asc + 8] = *(const f16x8*)(P.nlb + ga + 8);
            size_t gb2 = (size_t)bn2 * D + k0 + bkc;
            *(f16x8*)&sm.f1.B1h[bn2][bkc] = *(const f16x8*)(W1h + gb2);
            *(f16x8*)&sm.f1.B1l[bn2][bkc] = *(const f16x8*)(W1l + gb2);
            *(f16x8*)&sm.f1.B2h[bn2][bkc] = *(const f16x8*)(Wgh + gb2);
            *(f16x8*)&sm.f1.B2l[bn2][bkc] = *(const f16x8*)(Wgl + gb2);
          }
          __syncthreads();
          f16x8 a_h[2], a_l[2];
#pragma unroll
          for (int mt = 0; mt < 2; mt++) {
            a_h[mt] = *(const f16x8*)&sm.f1.Ah[w * 32 + mt * 16 + lm][lk];
            a_l[mt] = *(const f16x8*)&sm.f1.Al[w * 32 + mt * 16 + lm][lk];
          }
#pragma unroll
          for (int nt = 0; nt < 4; nt++) {
            f16x8 b_h = *(const f16x8*)&sm.f1.B1h[nt * 16 + lm][lk];
            f16x8 b_l = *(const f16x8*)&sm.f1.B1l[nt * 16 + lm][lk];
            f16x8 c_h = *(const f16x8*)&sm.f1.B2h[nt * 16 + lm][lk];
            f16x8 c_l = *(const f16x8*)&sm.f1.B2l[nt * 16 + lm][lk];
#pragma unroll
            for (int mt = 0; mt < 2; mt++) {
              f32x4 c1 = acc1[mt][nt];
              c1 = MFMA(a_h[mt], b_h, c1);
              c1 = MFMA(a_h[mt], b_l, c1);
              c1 = MFMA(a_l[mt], b_h, c1);
              acc1[mt][nt] = c1;
              f32x4 c2 = acc2[mt][nt];
              c2 = MFMA(a_h[mt], c_h, c2);
              c2 = MFMA(a_h[mt], c_l, c2);
              c2 = MFMA(a_l[mt], c_h, c2);
              acc2[mt][nt] = c2;
            }
          }
          __syncthreads();
        }
#pragma unroll
        for (int mt = 0; mt < 2; mt++)
#pragma unroll
          for (int nt = 0; nt < 4; nt++) {
            int col = col0 + nt * 16 + lm;
            float bb1 = b1f[e * FF + col], bb2 = bgf[e * FF + col];
#pragma unroll
            for (int r = 0; r < 4; r++) {
              int rit = w * 32 + mt * 16 + lg * 4 + r;
              if (rit < nv) {
                float z1 = acc1[mt][nt][r] + bb1;
                float zg = acc2[mt][nt][r] + bb2;
                float sl = z1 / (1.f + expf(-z1));
                float hv = sl * zg;
                f16 h16, l16; splitf(hv, h16, l16);
                P.hhb[(size_t)(base + rit) * FF + col] = h16;
                P.hlb[(size_t)(base + rit) * FF + col] = l16;
              }
            }
          }
      }
    }
    gridbar(P.bcnt, P.bgen);

    // ======== phase: FF2 (192 tiles) ========
    {
      bool active = (bid < 192);
      int mt0 = 0, cc = 0, e = -1;
      if (active) { mt0 = bid % 48; cc = bid / 48; e = P.te[mt0]; active = (e >= 0); }
      if (active) {
        const int base = P.tbase[mt0], nv = P.tnv[mt0];
        const int col0 = cc * 64;
        const f16* W2h = w2th + (size_t)e * FF * D + (size_t)col0 * FF;
        const f16* W2l = w2tl + (size_t)e * FF * D + (size_t)col0 * FF;
        const int asr = tid >> 1, asc = (tid & 1) * 16;
        const int bn2 = tid >> 2, bkc = (tid & 3) * 8;
        f32x4 acc[2][4] = {};
        for (int k0 = 0; k0 < FF; k0 += 32) {
          {
            size_t ga = (size_t)(base + asr) * FF + k0 + asc;
            *(f16x8*)&sm.f2.Ah[asr][asc]     = *(const f16x8*)(P.hhb + ga);
            *(f16x8*)&sm.f2.Ah[asr][asc + 8] = *(const f16x8*)(P.hhb + ga + 8);
            *(f16x8*)&sm.f2.Al[asr][asc]     = *(const f16x8*)(P.hlb + ga);
            *(f16x8*)&sm.f2.Al[asr][asc + 8] = *(const f16x8*)(P.hlb + ga + 8);
            size_t gb2 = (size_t)bn2 * FF + k0 + bkc;
            *(f16x8*)&sm.f2.Bh[bn2][bkc] = *(const f16x8*)(W2h + gb2);
            *(f16x8*)&sm.f2.Bl[bn2][bkc] = *(const f16x8*)(W2l + gb2);
          }
          __syncthreads();
          f16x8 a_h[2], a_l[2];
#pragma unroll
          for (int mt = 0; mt < 2; mt++) {
            a_h[mt] = *(const f16x8*)&sm.f2.Ah[w * 32 + mt * 16 + lm][lk];
            a_l[mt] = *(const f16x8*)&sm.f2.Al[w * 32 + mt * 16 + lm][lk];
          }
#pragma unroll
          for (int nt = 0; nt < 4; nt++) {
            f16x8 b_h = *(const f16x8*)&sm.f2.Bh[nt * 16 + lm][lk];
            f16x8 b_l = *(const f16x8*)&sm.f2.Bl[nt * 16 + lm][lk];
#pragma unroll
            for (int mt = 0; mt < 2; mt++) {
              f32x4 c = acc[mt][nt];
              c = MFMA(a_h[mt], b_h, c);
              c = MFMA(a_h[mt], b_l, c);
              c = MFMA(a_l[mt], b_h, c);
              acc[mt][nt] = c;
            }
          }
          __syncthreads();
        }
#pragma unroll
        for (int mt = 0; mt < 2; mt++)
#pragma unroll
          for (int nt = 0; nt < 4; nt++) {
            int col = col0 + nt * 16 + lm;
            float bb = b2f[e * D + col];
#pragma unroll
            for (int r = 0; r < 4; r++) {
              int rit = w * 32 + mt * 16 + lg * 4 + r;
              if (rit < nv) P.yb[(size_t)(base + rit) * D + col] = acc[mt][nt][r] + bb;
            }
          }
      }
    }
    gridbar(P.bcnt, P.bgen);

    // ======== phase: moe-sum + LN2 (512 groups, 2 per block) ========
    {
      float* dst = (l == LNUM - 1) ? P.out : P.xb;
      for (int g2 = 0; g2 < 2; g2++) {
        const int n = (bid + g2 * GRIDN) * 4 + w;
        const int p0 = P.tokpos[n * 2 + 0], p1 = P.tokpos[n * 2 + 1];
        float val[4], s1v = 0.f, s2v = 0.f;
#pragma unroll
        for (int j = 0; j < 4; j++) {
          int d = lane + 64 * j;
          float v = P.yb[(size_t)p0 * D + d] + P.yb[(size_t)p1 * D + d] + P.nb[(size_t)n * D + d];
          val[j] = v; s1v += v; s2v += v * v;
        }
#pragma unroll
        for (int m = 1; m < 64; m <<= 1) {
          s1v += __shfl_xor(s1v, m);
          s2v += __shfl_xor(s2v, m);
        }
        float mean = s1v * (1.f / D);
        float var = s2v * (1.f / D) - mean * mean;
        float rstd = rsqrtf(var + EPS);
#pragma unroll
        for (int j = 0; j < 4; j++) {
          int d = lane + 64 * j;
          float ov = (val[j] - mean) * rstd * l2s[d] + l2b[d];
          dst[(size_t)n * D + d] = ov;
          f16 h16, l16; splitf(ov, h16, l16);
          P.xh[(size_t)n * D + d] = h16;
          P.xl[(size_t)n * D + d] = l16;
        }
      }
    }
    gridbar(P.bcnt, P.bgen);
  }
}

extern "C" void kernel_launch(void* const* d_in, const int* in_sizes, int n_in,
                              void* d_out, int out_size, void* d_ws, size_t ws_size,
                              hipStream_t stream) {
  (void)in_sizes; (void)n_in; (void)out_size; (void)ws_size;
  const int*   tok = (const int*)d_in[0];
  const float* emb = (const float*)d_in[1];
  const float* Wq  = (const float*)d_in[2];
  const float* bq  = (const float*)d_in[3];
  const float* Wk  = (const float*)d_in[4];
  const float* bk  = (const float*)d_in[5];
  const float* Wv  = (const float*)d_in[6];
  const float* bv  = (const float*)d_in[7];
  const float* l1s = (const float*)d_in[8];
  const float* l1b = (const float*)d_in[9];
  const float* l2s = (const float*)d_in[10];
  const float* l2b = (const float*)d_in[11];
  const float* gW  = (const float*)d_in[12];
  const float* gb  = (const float*)d_in[13];
  const float* f1W = (const float*)d_in[14];
  const float* f1b = (const float*)d_in[15];
  const float* fgW = (const float*)d_in[16];
  const float* fgb = (const float*)d_in[17];
  const float* f2W = (const float*)d_in[18];
  const float* f2b = (const float*)d_in[19];

  char* p = (char*)d_ws;
  auto alloc = [&](size_t bytes) { char* r = p; p += (bytes + 255) & ~(size_t)255; return r; };
  MP P;
  P.tok = tok; P.emb = emb;
  P.bq = bq; P.bk = bk; P.bv = bv;
  P.l1s = l1s; P.l1b = l1b; P.l2s = l2s; P.l2b = l2b; P.gW = gW; P.gb = gb;
  P.f1b = f1b; P.fgb = fgb; P.f2b = f2b;
  P.out = (float*)d_out;
  P.xb = (float*)alloc((size_t)NT * D * 4);
  P.xh = (f16*)alloc((size_t)NT * D * 2);
  P.xl = (f16*)alloc((size_t)NT * D * 2);
  P.qhb = (f16*)alloc((size_t)NT * D * 2);
  P.qlb = (f16*)alloc((size_t)NT * D * 2);
  P.khb = (f16*)alloc((size_t)NT * D * 2);
  P.klb = (f16*)alloc((size_t)NT * D * 2);
  P.vhb = (f16*)alloc((size_t)NT * D * 2);
  P.vlb = (f16*)alloc((size_t)NT * D * 2);
  P.ob = (float*)alloc((size_t)NT * D * 4);
  P.nb = (float*)alloc((size_t)NT * D * 4);
  P.nhb = (f16*)alloc((size_t)NT * D * 2);
  P.nlb = (f16*)alloc((size_t)NT * D * 2);
  P.hhb = (f16*)alloc((size_t)PADROWS * FF * 2);
  P.hlb = (f16*)alloc((size_t)PADROWS * FF * 2);
  P.yb = (float*)alloc((size_t)PADROWS * D * 4);
  P.eidx   = (int*)alloc((size_t)NT * 2 * 4);
  P.rlist  = (int*)alloc((size_t)PADROWS * 4);
  P.tokpos = (int*)alloc((size_t)NT * 2 * 4);
  P.te     = (int*)alloc(MAXT * 4);
  P.tbase  = (int*)alloc(MAXT * 4);
  P.tnv    = (int*)alloc(MAXT * 4);
  P.bcnt   = (int*)alloc(256);
  P.bgen   = (int*)alloc(256);
  size_t qkvsz = (size_t)LNUM * D * D;
  size_t ffsz  = (size_t)LNUM * NE * D * FF;
  f16* wqh = (f16*)alloc(qkvsz * 2); f16* wql = (f16*)alloc(qkvsz * 2);
  f16* wkh = (f16*)alloc(qkvsz * 2); f16* wkl = (f16*)alloc(qkvsz * 2);
  f16* wvh = (f16*)alloc(qkvsz * 2); f16* wvl = (f16*)alloc(qkvsz * 2);
  f16* w1th = (f16*)alloc(ffsz * 2); f16* w1tl = (f16*)alloc(ffsz * 2);
  f16* wgth = (f16*)alloc(ffsz * 2); f16* wgtl = (f16*)alloc(ffsz * 2);
  f16* w2th = (f16*)alloc(ffsz * 2); f16* w2tl = (f16*)alloc(ffsz * 2);
  P.wqh = wqh; P.wql = wql; P.wkh = wkh; P.wkl = wkl; P.wvh = wvh; P.wvl = wvl;
  P.w1th = w1th; P.w1tl = w1tl; P.wgth = wgth; P.wgtl = wgtl; P.w2th = w2th; P.w2tl = w2tl;

  // ---- barrier state init (ws may be poisoned between correctness and timing) ----
  k_bzero<<<1, 1, 0, stream>>>(P.bcnt);

  // ---- weight prep (per launch; deterministic) ----
  k_wprep<<<dim3(D / 32, D / 32, LNUM), 256, 0, stream>>>(Wq, wqh, wql, D, D);
  k_wprep<<<dim3(D / 32, D / 32, LNUM), 256, 0, stream>>>(Wk, wkh, wkl, D, D);
  k_wprep<<<dim3(D / 32, D / 32, LNUM), 256, 0, stream>>>(Wv, wvh, wvl, D, D);
  k_wprep<<<dim3(FF / 32, D / 32, LNUM * NE), 256, 0, stream>>>(f1W, w1th, w1tl, D, FF);
  k_wprep<<<dim3(FF / 32, D / 32, LNUM * NE), 256, 0, stream>>>(fgW, wgth, wgtl, D, FF);
  k_wprep<<<dim3(D / 32, FF / 32, LNUM * NE), 256, 0, stream>>>(f2W, w2th, w2tl, FF, D);

  // ---- single megakernel (plain launch; software grid barriers) ----
  k_mega<<<dim3(GRIDN), dim3(256), 0, stream>>>(P);
}